// Round 18
// baseline (338.332 us; speedup 1.0000x reference)
//
#include <hip/hip_runtime.h>
#include <math.h>

// Contextual loss, N=1, C=256, H=W=96 -> S=9216.
// loss = log(S) - log( sum_j exp( -vcol_j ) )
//   vcol_j = min_i [ a_i * d_ij + ln S'_i ],  S'_i = sum_j exp(-a_i d_ij)
//   a_i = 2/(m_i+1e-5), m_i = min_j d_ij, d = clip((1-cos)/2, 0)
// R18 = R17 (224 µs: single GEMM + u8 fixed-point D in fragment layout,
// two BW streams) with:
//  (1) gemm epilogue algebra: rmax=max(acc*rT) replaces per-elem d chain
//      (m = max(.5-.5*rI*rmax,0) once/row); quantization = one FMA
//      qf = fma(t, -127.5*rI, 128) via rIqs LDS table + cvt_pk_u8 pack.
//      ~9 -> ~5 VALU ops/element.
//  (2) k_prep folded into k_rowsum_d tail (per-bi atomic counter; 24th
//      y-block computes {a/255, lnS'}). One fewer launch.

typedef short v8s __attribute__((ext_vector_type(8)));
typedef float v4f __attribute__((ext_vector_type(4)));

static constexpr int Sn = 9216;
static constexpr int Cn = 256;

// ws float offsets
static constexpr size_t OFF_MEAN = 0;                      // 256 floats
static constexpr size_t OFF_MROW = 256;                    // Sn uint bits (row min d)
static constexpr size_t OFF_WROW = 256 + 9216;             // Sn floats (S'_i)
static constexpr size_t OFF_VCOL = 256 + 2 * 9216;         // Sn uint bits (col min v)
static constexpr size_t OFF_SUM  = 256 + 3 * 9216;         // 1 float
static constexpr size_t OFF_CNT  = OFF_SUM + 1;            // 1 uint (fsum counter)
static constexpr size_t OFF_CNT2 = OFF_SUM + 2;            // 72 uints (rowsum counters)
static constexpr size_t OFF_ALW  = 256 + 4 * 9216;         // Sn float2 {a/255, lnS'}
static constexpr size_t OFF_IV   = 65536;                  // Sn*Cn bf16 (centered)
static constexpr size_t OFF_TV   = 65536 + (size_t)Sn * Cn / 2;
static constexpr size_t OFF_RI   = 65536 + (size_t)Sn * Cn;      // Sn floats
static constexpr size_t OFF_RT   = 65536 + (size_t)Sn * Cn + Sn; // Sn floats
// u8 D in fragment layout: tile chunk (bi,jt,wave) = 4 KB.
static constexpr size_t OFF_D_B  = (size_t)16 << 20;
static constexpr size_t D_BYTES  = (size_t)72 * 72 * 4 * 4096;  // 83 MB
static constexpr size_t NEED_B   = OFF_D_B + D_BYTES;

__device__ __forceinline__ unsigned bf16rne(float x) {
    unsigned u = __float_as_uint(x);
    return (u + 0x7FFFu + ((u >> 16) & 1u)) >> 16;
}

__device__ __forceinline__ void gload_lds16(const void* g, void* l) {
    __builtin_amdgcn_global_load_lds(
        (const __attribute__((address_space(1))) unsigned*)g,
        (__attribute__((address_space(3))) unsigned*)l, 16, 0, 0);
}

__device__ __forceinline__ unsigned pack_u8(float qf, int slot, unsigned old) {
#if __has_builtin(__builtin_amdgcn_cvt_pk_u8_f32)
    return __builtin_amdgcn_cvt_pk_u8_f32(qf, slot, old);
#else
    return old | (((unsigned)fminf(qf, 255.0f)) << (8 * slot));
#endif
}

// ------- per-channel mean of T (+ absorbed init of stat buffers) -------
__global__ void k_mean(const float* __restrict__ T, float* ws) {
    __shared__ float red[256];
    int idx = blockIdx.x * 256 + threadIdx.x;
    if (idx < Sn) {
        ((unsigned*)(ws + OFF_MROW))[idx] = 0x7F800000u;  // +inf
        ws[OFF_WROW + idx] = 0.0f;
        ((unsigned*)(ws + OFF_VCOL))[idx] = 0x7F800000u;  // +inf
    }
    if (idx == 0) ws[OFF_SUM] = 0.0f;
    if (idx == 1) ((unsigned*)ws)[OFF_CNT] = 0u;
    if (idx < 72) ((unsigned*)ws)[OFF_CNT2 + idx] = 0u;

    int c = blockIdx.x;
    float s = 0.f;
    for (int i = threadIdx.x; i < Sn; i += 256) s += T[(size_t)c * Sn + i];
    red[threadIdx.x] = s;
    __syncthreads();
    for (int off = 128; off > 0; off >>= 1) {
        if (threadIdx.x < off) red[threadIdx.x] += red[threadIdx.x + off];
        __syncthreads();
    }
    if (threadIdx.x == 0) ws[OFF_MEAN + c] = red[0] * (1.0f / Sn);
}

// ------- center, emit bf16 transposed [S][C], record 1/norm (single read) ----
// 576 blocks x 256 threads: 16 positions/block, 16 channel-groups of 16.
__global__ __launch_bounds__(256) void k_norm(const float* __restrict__ I,
                                              const float* __restrict__ T,
                                              float* ws) {
    __shared__ float mc[256];
    __shared__ float redI[16][17], redT[16][17];
    const int tid = threadIdx.x, sl = tid & 15, cq = tid >> 4;
    const int s = blockIdx.x * 16 + sl;
    mc[tid] = ws[OFF_MEAN + tid];
    __syncthreads();
    unsigned short* Iv = (unsigned short*)(ws + OFF_IV);
    unsigned short* Tv = (unsigned short*)(ws + OFF_TV);
    float si = 0.f, st = 0.f;
    unsigned iw[8], tw[8];
#pragma unroll
    for (int h = 0; h < 8; ++h) {
        int c0 = cq * 16 + 2 * h, c1 = c0 + 1;
        float xi0 = I[(size_t)c0 * Sn + s] - mc[c0];
        float xi1 = I[(size_t)c1 * Sn + s] - mc[c1];
        float xt0 = T[(size_t)c0 * Sn + s] - mc[c0];
        float xt1 = T[(size_t)c1 * Sn + s] - mc[c1];
        si += xi0 * xi0 + xi1 * xi1;
        st += xt0 * xt0 + xt1 * xt1;
        iw[h] = bf16rne(xi0) | (bf16rne(xi1) << 16);
        tw[h] = bf16rne(xt0) | (bf16rne(xt1) << 16);
    }
    uint4* Ivq = (uint4*)(Iv + (size_t)s * Cn + cq * 16);
    uint4* Tvq = (uint4*)(Tv + (size_t)s * Cn + cq * 16);
    Ivq[0] = make_uint4(iw[0], iw[1], iw[2], iw[3]);
    Ivq[1] = make_uint4(iw[4], iw[5], iw[6], iw[7]);
    Tvq[0] = make_uint4(tw[0], tw[1], tw[2], tw[3]);
    Tvq[1] = make_uint4(tw[4], tw[5], tw[6], tw[7]);
    redI[sl][cq] = si;
    redT[sl][cq] = st;
    __syncthreads();
    if (tid < 16) {
        float a = 0.f, b = 0.f;
#pragma unroll
        for (int k = 0; k < 16; ++k) {
            a += redI[tid][k];
            b += redT[tid][k];
        }
        ws[OFF_RI + blockIdx.x * 16 + tid] = 1.0f / fmaxf(sqrtf(a), 1e-12f);
        ws[OFF_RT + blockIdx.x * 16 + tid] = 1.0f / fmaxf(sqrtf(b), 1e-12f);
    }
}

// ---- r3/r8-proven staging: 16 KB K-slices, 8-chunk XOR swizzle ----
__device__ __forceinline__ void stage_slice(const char* Gb, char* lds,
                                            int kcs, int tid) {
    const int lane = tid & 63, wave = tid >> 6;
#pragma unroll
    for (int w = 0; w < 4; ++w) {
        int gi = wave * 4 + w;
        int row = gi * 8 + (lane >> 3);
        int p = lane & 7;
        int c = p ^ (row & 7);
        const char* g = Gb + (size_t)row * 512 + kcs * 128 + c * 16;
        gload_lds16(g, lds + gi * 1024);
    }
}

// A fragments straight from global (L2): 32 independent 16 B loads.
__device__ __forceinline__ void load_A(const v8s* __restrict__ Aq, int row0,
                                       int quad, int l15, v8s fa[4][8]) {
#pragma unroll
    for (int mt = 0; mt < 4; ++mt) {
        size_t row = row0 + mt * 16 + l15;
#pragma unroll
        for (int kk = 0; kk < 8; ++kk)
            fa[mt][kk] = Aq[row * 32 + kk * 4 + quad];
    }
}

__device__ __forceinline__ void tile_mma(const char* Bb, char* lds, int tid,
                                         const v8s fa[4][8], v4f acc[4][4]) {
    const int lane = tid & 63, wave = tid >> 6;
    const int wn = wave & 1, quad = (lane >> 4) & 3, l15 = lane & 15;
#pragma unroll
    for (int kc = 0; kc < 4; ++kc) {
        __syncthreads();
        stage_slice(Bb, lds, kc, tid);
        __syncthreads();
#pragma unroll
        for (int ks = 0; ks < 2; ++ks) {
            int c = ks * 4 + quad;
#pragma unroll
            for (int nt = 0; nt < 4; ++nt) {
                int row = wn * 64 + nt * 16 + l15;
                int p = c ^ (row & 7);
                v8s fb = *(const v8s*)(lds + row * 128 + p * 16);
#pragma unroll
                for (int mt = 0; mt < 4; ++mt)
                    acc[mt][nt] = __builtin_amdgcn_mfma_f32_16x16x32_bf16(
                        fa[mt][kc * 2 + ks], fb, acc[mt][nt], 0, 0, 0);
            }
        }
    }
}

// ======== BIG-WS pass 1: GEMM once, store u8 D fragments + rowmin ========
__global__ __launch_bounds__(256, 2) void k_gemm_d(float* ws) {
    __shared__ __align__(16) char Bsb[16384];
    __shared__ float rIs[128], rIqs[128], rTs[128];
    const v8s* Ivq = (const v8s*)(ws + OFF_IV);
    const char* Tvb = (const char*)(ws + OFF_TV);
    char* Dp = (char*)ws + OFF_D_B;
    const int tid = threadIdx.x, lane = tid & 63, wave = tid >> 6;
    const int wm = wave >> 1, wn = wave & 1, quad = (lane >> 4) & 3, l15 = lane & 15;
    const int bi = blockIdx.x, i0 = bi * 128;
    v8s fa[4][8];
    load_A(Ivq, i0 + wm * 64, quad, l15, fa);
    if (tid < 128) {
        float rI = ws[OFF_RI + i0 + tid];
        rIs[tid] = rI;
        rIqs[tid] = -127.5f * rI;
    }
    float rmax[4][4];
#pragma unroll
    for (int mt = 0; mt < 4; ++mt)
#pragma unroll
        for (int r = 0; r < 4; ++r) rmax[mt][r] = -INFINITY;
    for (int t = 0; t < 9; ++t) {
        int jt = blockIdx.y * 9 + t;
        __syncthreads();  // epilogue readers of rTs done
        if (tid < 128) rTs[tid] = ws[OFF_RT + jt * 128 + tid];
        v4f acc[4][4];
#pragma unroll
        for (int mt = 0; mt < 4; ++mt)
#pragma unroll
            for (int nt = 0; nt < 4; ++nt)
#pragma unroll
                for (int r = 0; r < 4; ++r) acc[mt][nt][r] = 0.f;
        tile_mma(Tvb + (size_t)jt * 128 * 512, Bsb, tid, fa, acc);
        char* cb = Dp + (((size_t)bi * 72 + jt) * 4 + wave) * 4096;
#pragma unroll
        for (int mt = 0; mt < 4; ++mt) {
            unsigned words[4];
#pragma unroll
            for (int nt = 0; nt < 4; ++nt) {
                float rT = rTs[wn * 64 + nt * 16 + l15];
                unsigned w = 0;
#pragma unroll
                for (int k = 0; k < 4; ++k) {
                    float rIq = rIqs[wm * 64 + mt * 16 + quad * 4 + k];
                    float tt = acc[mt][nt][k] * rT;
                    rmax[mt][k] = fmaxf(rmax[mt][k], tt);
                    float qf = fmaxf(fmaf(tt, rIq, 128.0f), 0.0f);
                    w = pack_u8(qf, k, w);
                }
                words[nt] = w;
            }
            *(uint4*)(cb + mt * 1024 + lane * 16) =
                make_uint4(words[0], words[1], words[2], words[3]);
        }
    }
#pragma unroll
    for (int mt = 0; mt < 4; ++mt)
#pragma unroll
        for (int r = 0; r < 4; ++r) {
            float rm = rmax[mt][r];
            for (int off = 1; off < 16; off <<= 1)
                rm = fmaxf(rm, __shfl_xor(rm, off, 64));
            if (l15 == 0) {
                float rI = rIs[wm * 64 + mt * 16 + quad * 4 + r];
                float m = fmaxf(0.5f - 0.5f * rI * rm, 0.0f);
                atomicMin((unsigned*)(ws + OFF_MROW) + i0 + wm * 64 + mt * 16 + quad * 4 + r,
                          __float_as_uint(m));
            }
        }
}

// ---- pass 2 (stream): S'_i = sum_j exp(-a_i d_ij) over u8 D fragments ----
// grid (72, 24). c1 (incl. /255) broadcast table in LDS -> no spill.
// Tail: 24th y-block per bi computes {a/255, lnS'} (k_prep folded in).
__global__ void k_rowsum_d(float* ws) {
    __shared__ float c1s[128];
    __shared__ unsigned lastflag;
    const char* Dp = (const char*)ws + OFF_D_B;
    const int tid = threadIdx.x, lane = tid & 63, wave = tid >> 6;
    const int wm = wave >> 1, quad = (lane >> 4) & 3, l15 = lane & 15;
    const int bi = blockIdx.x;
    if (tid < 128) {
        float mm = __uint_as_float(((unsigned*)(ws + OFF_MROW))[bi * 128 + tid]);
        // -a*log2e/255
        c1s[tid] = -1.4426950408889634f / 255.0f * 2.0f / (mm + 1e-5f);
    }
    __syncthreads();
    float run[4][4];
#pragma unroll
    for (int mt = 0; mt < 4; ++mt)
#pragma unroll
        for (int r = 0; r < 4; ++r) run[mt][r] = 0.f;
    for (int t = 0; t < 3; ++t) {
        int jt = blockIdx.y * 3 + t;
        const char* cb = Dp + (((size_t)bi * 72 + jt) * 4 + wave) * 4096;
#pragma unroll
        for (int mt = 0; mt < 4; ++mt) {
            uint4 W = *(const uint4*)(cb + mt * 1024 + lane * 16);
            unsigned wd[4] = {W.x, W.y, W.z, W.w};
#pragma unroll
            for (int k = 0; k < 4; ++k) {
                float c1 = c1s[wm * 64 + mt * 16 + quad * 4 + k];
#pragma unroll
                for (int nt = 0; nt < 4; ++nt) {
                    float dq = (float)((wd[nt] >> (8 * k)) & 0xffu);
                    run[mt][k] += __builtin_amdgcn_exp2f(c1 * dq);
                }
            }
        }
    }
#pragma unroll
    for (int mt = 0; mt < 4; ++mt)
#pragma unroll
        for (int r = 0; r < 4; ++r) {
            float s = run[mt][r];
            for (int off = 1; off < 16; off <<= 1)
                s += __shfl_xor(s, off, 64);
            if (l15 == 0)
                atomicAdd(ws + OFF_WROW + bi * 128 + wm * 64 + mt * 16 + quad * 4 + r, s);
        }
    // ---- folded k_prep: last y-block for this bi writes {a/255, lnS'} ----
    __threadfence();
    if (tid == 0) lastflag = atomicAdd((unsigned*)ws + OFF_CNT2 + bi, 1u);
    __syncthreads();
    if (lastflag == 23u && tid < 128) {
        int i = bi * 128 + tid;
        float sp = atomicAdd(ws + OFF_WROW + i, 0.0f);  // coherent read
        float mm = __uint_as_float(((unsigned*)(ws + OFF_MROW))[i]);
        float a = (2.0f / 255.0f) / (mm + 1e-5f);
        ((float2*)(ws + OFF_ALW))[i] = make_float2(a, logf(sp));
    }
}

// ---- pass 3 (stream): vcol_j = min_i [a_i d_ij + lnS'_i] over u8 D ----
// grid (72, 24). alw broadcast table in LDS -> no spill.
__global__ void k_colmin_d(float* ws) {
    __shared__ float2 alws[128];
    const char* Dp = (const char*)ws + OFF_D_B;
    const float2* alw = (const float2*)(ws + OFF_ALW);
    const int tid = threadIdx.x, lane = tid & 63, wave = tid >> 6;
    const int wm = wave >> 1, wn = wave & 1, quad = (lane >> 4) & 3, l15 = lane & 15;
    const int jt = blockIdx.x;
    float vmin[4];
#pragma unroll
    for (int nt = 0; nt < 4; ++nt) vmin[nt] = INFINITY;
    for (int t = 0; t < 3; ++t) {
        int bi = blockIdx.y * 3 + t;
        __syncthreads();  // previous iteration's readers done
        if (tid < 128) alws[tid] = alw[bi * 128 + tid];
        __syncthreads();
        const char* cb = Dp + (((size_t)bi * 72 + jt) * 4 + wave) * 4096;
#pragma unroll
        for (int mt = 0; mt < 4; ++mt) {
            uint4 W = *(const uint4*)(cb + mt * 1024 + lane * 16);
            unsigned wd[4] = {W.x, W.y, W.z, W.w};
#pragma unroll
            for (int k = 0; k < 4; ++k) {
                float2 al = alws[wm * 64 + mt * 16 + quad * 4 + k];
#pragma unroll
                for (int nt = 0; nt < 4; ++nt) {
                    float dq = (float)((wd[nt] >> (8 * k)) & 0xffu);
                    vmin[nt] = fminf(vmin[nt], al.x * dq + al.y);
                }
            }
        }
    }
    // reduce across quads (lane bits 4,5): cols shared by same l15
#pragma unroll
    for (int nt = 0; nt < 4; ++nt) {
        float v = vmin[nt];
        v = fminf(v, __shfl_xor(v, 16, 64));
        v = fminf(v, __shfl_xor(v, 32, 64));
        if (quad == 0) {
            v = fmaxf(v, 0.0f);  // keep positive-bit atomicMin valid
            atomicMin((unsigned*)(ws + OFF_VCOL) + jt * 128 + wn * 64 + nt * 16 + l15,
                      __float_as_uint(v));
        }
    }
}

// ======== FALLBACK (small ws): r8 3-GEMM path, with RI/RT scaling ========
__global__ __launch_bounds__(256, 2) void k_rowmin(float* ws) {
    __shared__ __align__(16) char Bsb[16384];
    __shared__ float rIs[128], rTs[128];
    const v8s* Ivq = (const v8s*)(ws + OFF_IV);
    const char* Tvb = (const char*)(ws + OFF_TV);
    const int tid = threadIdx.x, lane = tid & 63, wave = tid >> 6;
    const int wm = wave >> 1, wn = wave & 1, quad = (lane >> 4) & 3, l15 = lane & 15;
    const int i0 = blockIdx.x * 128;
    v8s fa[4][8];
    load_A(Ivq, i0 + wm * 64, quad, l15, fa);
    if (tid < 128) rIs[tid] = ws[OFF_RI + i0 + tid];
    float mv[4][4];
#pragma unroll
    for (int mt = 0; mt < 4; ++mt)
#pragma unroll
        for (int r = 0; r < 4; ++r) mv[mt][r] = INFINITY;
    for (int t = 0; t < 4; ++t) {
        int j0 = (blockIdx.y * 4 + t) * 128;
        __syncthreads();
        if (tid < 128) rTs[tid] = ws[OFF_RT + j0 + tid];
        v4f acc[4][4];
#pragma unroll
        for (int mt = 0; mt < 4; ++mt)
#pragma unroll
            for (int nt = 0; nt < 4; ++nt)
#pragma unroll
                for (int r = 0; r < 4; ++r) acc[mt][nt][r] = 0.f;
        tile_mma(Tvb + (size_t)j0 * 512, Bsb, tid, fa, acc);
#pragma unroll
        for (int mt = 0; mt < 4; ++mt)
#pragma unroll
            for (int nt = 0; nt < 4; ++nt) {
                float rT = rTs[wn * 64 + nt * 16 + l15];
#pragma unroll
                for (int r = 0; r < 4; ++r) {
                    float rI = rIs[wm * 64 + mt * 16 + quad * 4 + r];
                    float d = fmaxf(0.5f - 0.5f * acc[mt][nt][r] * rI * rT, 0.0f);
                    mv[mt][r] = fminf(mv[mt][r], d);
                }
            }
    }
#pragma unroll
    for (int mt = 0; mt < 4; ++mt)
#pragma unroll
        for (int r = 0; r < 4; ++r) {
            float m = mv[mt][r];
            for (int off = 1; off < 16; off <<= 1)
                m = fminf(m, __shfl_xor(m, off, 64));
            if (l15 == 0)
                atomicMin((unsigned*)(ws + OFF_MROW) + i0 + wm * 64 + mt * 16 + quad * 4 + r,
                          __float_as_uint(m));
        }
}

__global__ __launch_bounds__(256, 2) void k_rowsum(float* ws) {
    __shared__ __align__(16) char Bsb[16384];
    __shared__ float rIs[128], rTs[128];
    const v8s* Ivq = (const v8s*)(ws + OFF_IV);
    const char* Tvb = (const char*)(ws + OFF_TV);
    const int tid = threadIdx.x, lane = tid & 63, wave = tid >> 6;
    const int wm = wave >> 1, wn = wave & 1, quad = (lane >> 4) & 3, l15 = lane & 15;
    const int i0 = blockIdx.x * 128;
    v8s fa[4][8];
    load_A(Ivq, i0 + wm * 64, quad, l15, fa);
    if (tid < 128) rIs[tid] = ws[OFF_RI + i0 + tid];
    float c1[4][4], run[4][4];
#pragma unroll
    for (int mt = 0; mt < 4; ++mt)
#pragma unroll
        for (int r = 0; r < 4; ++r) {
            int i = i0 + wm * 64 + mt * 16 + quad * 4 + r;
            float mm = __uint_as_float(((unsigned*)(ws + OFF_MROW))[i]);
            c1[mt][r] = -1.4426950408889634f * 2.0f / (mm + 1e-5f);
            run[mt][r] = 0.f;
        }
    for (int t = 0; t < 4; ++t) {
        int j0 = (blockIdx.y * 4 + t) * 128;
        __syncthreads();
        if (tid < 128) rTs[tid] = ws[OFF_RT + j0 + tid];
        v4f acc[4][4];
#pragma unroll
        for (int mt = 0; mt < 4; ++mt)
#pragma unroll
            for (int nt = 0; nt < 4; ++nt)
#pragma unroll
                for (int r = 0; r < 4; ++r) acc[mt][nt][r] = 0.f;
        tile_mma(Tvb + (size_t)j0 * 512, Bsb, tid, fa, acc);
#pragma unroll
        for (int mt = 0; mt < 4; ++mt)
#pragma unroll
            for (int nt = 0; nt < 4; ++nt) {
                float rT = rTs[wn * 64 + nt * 16 + l15];
#pragma unroll
                for (int r = 0; r < 4; ++r) {
                    float rI = rIs[wm * 64 + mt * 16 + quad * 4 + r];
                    float d = fmaxf(0.5f - 0.5f * acc[mt][nt][r] * rI * rT, 0.0f);
                    run[mt][r] += __builtin_amdgcn_exp2f(c1[mt][r] * d);
                }
            }
    }
#pragma unroll
    for (int mt = 0; mt < 4; ++mt)
#pragma unroll
        for (int r = 0; r < 4; ++r) {
            float s = run[mt][r];
            for (int off = 1; off < 16; off <<= 1)
                s += __shfl_xor(s, off, 64);
            if (l15 == 0)
                atomicAdd(ws + OFF_WROW + i0 + wm * 64 + mt * 16 + quad * 4 + r, s);
        }
}

__global__ __launch_bounds__(256, 2) void k_colmin(float* ws) {
    __shared__ __align__(16) char Bsb[16384];
    __shared__ float rTsb[128], rIst[128];
    const char* Ivb = (const char*)(ws + OFF_IV);
    const v8s* Tvq = (const v8s*)(ws + OFF_TV);
    const int tid = threadIdx.x, lane = tid & 63, wave = tid >> 6;
    const int wm = wave >> 1, wn = wave & 1, quad = (lane >> 4) & 3, l15 = lane & 15;
    const int j0 = blockIdx.x * 128;
    v8s fa[4][8];
    load_A(Tvq, j0 + wm * 64, quad, l15, fa);
    if (tid < 128) rTsb[tid] = ws[OFF_RT + j0 + tid];
    float vmin[4][4];
#pragma unroll
    for (int mt = 0; mt < 4; ++mt)
#pragma unroll
        for (int r = 0; r < 4; ++r) vmin[mt][r] = INFINITY;
    for (int t = 0; t < 4; ++t) {
        int ib = (blockIdx.y * 4 + t) * 128;
        __syncthreads();
        if (tid < 128) rIst[tid] = ws[OFF_RI + ib + tid];
        v4f acc[4][4];
#pragma unroll
        for (int mt = 0; mt < 4; ++mt)
#pragma unroll
            for (int nt = 0; nt < 4; ++nt)
#pragma unroll
                for (int r = 0; r < 4; ++r) acc[mt][nt][r] = 0.f;
        tile_mma(Ivb + (size_t)ib * 512, Bsb, tid, fa, acc);  // acc = raw[j][i]
#pragma unroll
        for (int nt = 0; nt < 4; ++nt) {
            int i = ib + wn * 64 + nt * 16 + l15;
            float rI = rIst[wn * 64 + nt * 16 + l15];
            float mm = __uint_as_float(((unsigned*)(ws + OFF_MROW))[i]);
            float a = 2.0f / (mm + 1e-5f);
            float lw = __builtin_amdgcn_logf(ws[OFF_WROW + i]) * 0.6931471805599453f;
#pragma unroll
            for (int mt = 0; mt < 4; ++mt)
#pragma unroll
                for (int r = 0; r < 4; ++r) {
                    float rT = rTsb[wm * 64 + mt * 16 + quad * 4 + r];
                    float d = fmaxf(0.5f - 0.5f * acc[mt][nt][r] * rI * rT, 0.0f);
                    vmin[mt][r] = fminf(vmin[mt][r], a * d + lw);
                }
        }
    }
#pragma unroll
    for (int mt = 0; mt < 4; ++mt)
#pragma unroll
        for (int r = 0; r < 4; ++r) {
            float v = vmin[mt][r];
            for (int off = 1; off < 16; off <<= 1)
                v = fminf(v, __shfl_xor(v, off, 64));
            if (l15 == 0)
                atomicMin((unsigned*)(ws + OFF_VCOL) + j0 + wm * 64 + mt * 16 + quad * 4 + r,
                          __float_as_uint(v));
        }
}

// ------- final: parallel sum; last block writes the scalar result -------
__global__ void k_fsum(float* ws, float* __restrict__ out) {
    __shared__ float red[256];
    int j0 = blockIdx.x * 256 + threadIdx.x;
    float s = expf(-__uint_as_float(((const unsigned*)(ws + OFF_VCOL))[j0]));
    red[threadIdx.x] = s;
    __syncthreads();
    for (int off = 128; off > 0; off >>= 1) {
        if (threadIdx.x < off) red[threadIdx.x] += red[threadIdx.x + off];
        __syncthreads();
    }
    if (threadIdx.x == 0) {
        atomicAdd(ws + OFF_SUM, red[0]);
        __threadfence();
        unsigned done = atomicAdd((unsigned*)ws + OFF_CNT, 1u);
        if (done == 35u) {
            float tot = atomicAdd(ws + OFF_SUM, 0.0f);  // coherent read
            out[0] = logf((float)Sn) - logf(tot);
        }
    }
}

extern "C" void kernel_launch(void* const* d_in, const int* in_sizes, int n_in,
                              void* d_out, int out_size, void* d_ws, size_t ws_size,
                              hipStream_t stream) {
    const float* I = (const float*)d_in[0];
    const float* T = (const float*)d_in[1];
    float* ws = (float*)d_ws;
    float* out = (float*)d_out;

    k_mean<<<Cn, 256, 0, stream>>>(T, ws);
    k_norm<<<Sn / 16, 256, 0, stream>>>(I, T, ws);
    if (ws_size >= NEED_B) {
        k_gemm_d<<<dim3(72, 8), 256, 0, stream>>>(ws);
        k_rowsum_d<<<dim3(72, 24), 256, 0, stream>>>(ws);
        k_colmin_d<<<dim3(72, 24), 256, 0, stream>>>(ws);
    } else {
        k_rowmin<<<dim3(72, 18), 256, 0, stream>>>(ws);
        k_rowsum<<<dim3(72, 18), 256, 0, stream>>>(ws);
        k_colmin<<<dim3(72, 18), 256, 0, stream>>>(ws);
    }
    k_fsum<<<36, 256, 0, stream>>>(ws, out);
}

// Round 19
// 211.838 us; speedup vs baseline: 1.5971x; 1.5971x over previous
//
#include <hip/hip_runtime.h>
#include <math.h>

// Contextual loss, N=1, C=256, H=W=96 -> S=9216.
// loss = log(S) - log( sum_j exp( -vcol_j ) )
//   vcol_j = min_i [ a_i * d_ij + ln S'_i ],  S'_i = sum_j exp(-a_i d_ij)
//   a_i = 2/(m_i+1e-5), m_i = min_j d_ij, d = clip((1-cos)/2, 0)
// R19 = R18 minus the k_prep fold (REVERTED: the per-block __threadfence
// in rowsum_d's tail cost +130 µs -- device-scope fences in a hot stream
// kernel destroy the L2 read pipeline; a separate 5 µs launch is cheap).
// Keeps r18's gemm epilogue algebra (rmax + fma-quantize + cvt_pk_u8),
// which this round measures in isolation.

typedef short v8s __attribute__((ext_vector_type(8)));
typedef float v4f __attribute__((ext_vector_type(4)));

static constexpr int Sn = 9216;
static constexpr int Cn = 256;

// ws float offsets
static constexpr size_t OFF_MEAN = 0;                      // 256 floats
static constexpr size_t OFF_MROW = 256;                    // Sn uint bits (row min d)
static constexpr size_t OFF_WROW = 256 + 9216;             // Sn floats (S'_i)
static constexpr size_t OFF_VCOL = 256 + 2 * 9216;         // Sn uint bits (col min v)
static constexpr size_t OFF_SUM  = 256 + 3 * 9216;         // 1 float
static constexpr size_t OFF_CNT  = OFF_SUM + 1;            // 1 uint (fsum counter)
static constexpr size_t OFF_ALW  = 256 + 4 * 9216;         // Sn float2 {a/255, lnS'}
static constexpr size_t OFF_IV   = 65536;                  // Sn*Cn bf16 (centered)
static constexpr size_t OFF_TV   = 65536 + (size_t)Sn * Cn / 2;
static constexpr size_t OFF_RI   = 65536 + (size_t)Sn * Cn;      // Sn floats
static constexpr size_t OFF_RT   = 65536 + (size_t)Sn * Cn + Sn; // Sn floats
// u8 D in fragment layout: tile chunk (bi,jt,wave) = 4 KB.
static constexpr size_t OFF_D_B  = (size_t)16 << 20;
static constexpr size_t D_BYTES  = (size_t)72 * 72 * 4 * 4096;  // 83 MB
static constexpr size_t NEED_B   = OFF_D_B + D_BYTES;

__device__ __forceinline__ unsigned bf16rne(float x) {
    unsigned u = __float_as_uint(x);
    return (u + 0x7FFFu + ((u >> 16) & 1u)) >> 16;
}

__device__ __forceinline__ void gload_lds16(const void* g, void* l) {
    __builtin_amdgcn_global_load_lds(
        (const __attribute__((address_space(1))) unsigned*)g,
        (__attribute__((address_space(3))) unsigned*)l, 16, 0, 0);
}

__device__ __forceinline__ unsigned pack_u8(float qf, int slot, unsigned old) {
#if __has_builtin(__builtin_amdgcn_cvt_pk_u8_f32)
    return __builtin_amdgcn_cvt_pk_u8_f32(qf, slot, old);
#else
    return old | (((unsigned)fminf(qf, 255.0f)) << (8 * slot));
#endif
}

// ------- per-channel mean of T (+ absorbed init of stat buffers) -------
__global__ void k_mean(const float* __restrict__ T, float* ws) {
    __shared__ float red[256];
    int idx = blockIdx.x * 256 + threadIdx.x;
    if (idx < Sn) {
        ((unsigned*)(ws + OFF_MROW))[idx] = 0x7F800000u;  // +inf
        ws[OFF_WROW + idx] = 0.0f;
        ((unsigned*)(ws + OFF_VCOL))[idx] = 0x7F800000u;  // +inf
    }
    if (idx == 0) ws[OFF_SUM] = 0.0f;
    if (idx == 1) ((unsigned*)ws)[OFF_CNT] = 0u;

    int c = blockIdx.x;
    float s = 0.f;
    for (int i = threadIdx.x; i < Sn; i += 256) s += T[(size_t)c * Sn + i];
    red[threadIdx.x] = s;
    __syncthreads();
    for (int off = 128; off > 0; off >>= 1) {
        if (threadIdx.x < off) red[threadIdx.x] += red[threadIdx.x + off];
        __syncthreads();
    }
    if (threadIdx.x == 0) ws[OFF_MEAN + c] = red[0] * (1.0f / Sn);
}

// ------- center, emit bf16 transposed [S][C], record 1/norm (single read) ----
// 576 blocks x 256 threads: 16 positions/block, 16 channel-groups of 16.
__global__ __launch_bounds__(256) void k_norm(const float* __restrict__ I,
                                              const float* __restrict__ T,
                                              float* ws) {
    __shared__ float mc[256];
    __shared__ float redI[16][17], redT[16][17];
    const int tid = threadIdx.x, sl = tid & 15, cq = tid >> 4;
    const int s = blockIdx.x * 16 + sl;
    mc[tid] = ws[OFF_MEAN + tid];
    __syncthreads();
    unsigned short* Iv = (unsigned short*)(ws + OFF_IV);
    unsigned short* Tv = (unsigned short*)(ws + OFF_TV);
    float si = 0.f, st = 0.f;
    unsigned iw[8], tw[8];
#pragma unroll
    for (int h = 0; h < 8; ++h) {
        int c0 = cq * 16 + 2 * h, c1 = c0 + 1;
        float xi0 = I[(size_t)c0 * Sn + s] - mc[c0];
        float xi1 = I[(size_t)c1 * Sn + s] - mc[c1];
        float xt0 = T[(size_t)c0 * Sn + s] - mc[c0];
        float xt1 = T[(size_t)c1 * Sn + s] - mc[c1];
        si += xi0 * xi0 + xi1 * xi1;
        st += xt0 * xt0 + xt1 * xt1;
        iw[h] = bf16rne(xi0) | (bf16rne(xi1) << 16);
        tw[h] = bf16rne(xt0) | (bf16rne(xt1) << 16);
    }
    uint4* Ivq = (uint4*)(Iv + (size_t)s * Cn + cq * 16);
    uint4* Tvq = (uint4*)(Tv + (size_t)s * Cn + cq * 16);
    Ivq[0] = make_uint4(iw[0], iw[1], iw[2], iw[3]);
    Ivq[1] = make_uint4(iw[4], iw[5], iw[6], iw[7]);
    Tvq[0] = make_uint4(tw[0], tw[1], tw[2], tw[3]);
    Tvq[1] = make_uint4(tw[4], tw[5], tw[6], tw[7]);
    redI[sl][cq] = si;
    redT[sl][cq] = st;
    __syncthreads();
    if (tid < 16) {
        float a = 0.f, b = 0.f;
#pragma unroll
        for (int k = 0; k < 16; ++k) {
            a += redI[tid][k];
            b += redT[tid][k];
        }
        ws[OFF_RI + blockIdx.x * 16 + tid] = 1.0f / fmaxf(sqrtf(a), 1e-12f);
        ws[OFF_RT + blockIdx.x * 16 + tid] = 1.0f / fmaxf(sqrtf(b), 1e-12f);
    }
}

// ---- r3/r8-proven staging: 16 KB K-slices, 8-chunk XOR swizzle ----
__device__ __forceinline__ void stage_slice(const char* Gb, char* lds,
                                            int kcs, int tid) {
    const int lane = tid & 63, wave = tid >> 6;
#pragma unroll
    for (int w = 0; w < 4; ++w) {
        int gi = wave * 4 + w;
        int row = gi * 8 + (lane >> 3);
        int p = lane & 7;
        int c = p ^ (row & 7);
        const char* g = Gb + (size_t)row * 512 + kcs * 128 + c * 16;
        gload_lds16(g, lds + gi * 1024);
    }
}

// A fragments straight from global (L2): 32 independent 16 B loads.
__device__ __forceinline__ void load_A(const v8s* __restrict__ Aq, int row0,
                                       int quad, int l15, v8s fa[4][8]) {
#pragma unroll
    for (int mt = 0; mt < 4; ++mt) {
        size_t row = row0 + mt * 16 + l15;
#pragma unroll
        for (int kk = 0; kk < 8; ++kk)
            fa[mt][kk] = Aq[row * 32 + kk * 4 + quad];
    }
}

__device__ __forceinline__ void tile_mma(const char* Bb, char* lds, int tid,
                                         const v8s fa[4][8], v4f acc[4][4]) {
    const int lane = tid & 63, wave = tid >> 6;
    const int wn = wave & 1, quad = (lane >> 4) & 3, l15 = lane & 15;
#pragma unroll
    for (int kc = 0; kc < 4; ++kc) {
        __syncthreads();
        stage_slice(Bb, lds, kc, tid);
        __syncthreads();
#pragma unroll
        for (int ks = 0; ks < 2; ++ks) {
            int c = ks * 4 + quad;
#pragma unroll
            for (int nt = 0; nt < 4; ++nt) {
                int row = wn * 64 + nt * 16 + l15;
                int p = c ^ (row & 7);
                v8s fb = *(const v8s*)(lds + row * 128 + p * 16);
#pragma unroll
                for (int mt = 0; mt < 4; ++mt)
                    acc[mt][nt] = __builtin_amdgcn_mfma_f32_16x16x32_bf16(
                        fa[mt][kc * 2 + ks], fb, acc[mt][nt], 0, 0, 0);
            }
        }
    }
}

// ======== BIG-WS pass 1: GEMM once, store u8 D fragments + rowmin ========
__global__ __launch_bounds__(256, 2) void k_gemm_d(float* ws) {
    __shared__ __align__(16) char Bsb[16384];
    __shared__ float rIs[128], rIqs[128], rTs[128];
    const v8s* Ivq = (const v8s*)(ws + OFF_IV);
    const char* Tvb = (const char*)(ws + OFF_TV);
    char* Dp = (char*)ws + OFF_D_B;
    const int tid = threadIdx.x, lane = tid & 63, wave = tid >> 6;
    const int wm = wave >> 1, wn = wave & 1, quad = (lane >> 4) & 3, l15 = lane & 15;
    const int bi = blockIdx.x, i0 = bi * 128;
    v8s fa[4][8];
    load_A(Ivq, i0 + wm * 64, quad, l15, fa);
    if (tid < 128) {
        float rI = ws[OFF_RI + i0 + tid];
        rIs[tid] = rI;
        rIqs[tid] = -127.5f * rI;
    }
    float rmax[4][4];
#pragma unroll
    for (int mt = 0; mt < 4; ++mt)
#pragma unroll
        for (int r = 0; r < 4; ++r) rmax[mt][r] = -INFINITY;
    for (int t = 0; t < 9; ++t) {
        int jt = blockIdx.y * 9 + t;
        __syncthreads();  // epilogue readers of rTs done
        if (tid < 128) rTs[tid] = ws[OFF_RT + jt * 128 + tid];
        v4f acc[4][4];
#pragma unroll
        for (int mt = 0; mt < 4; ++mt)
#pragma unroll
            for (int nt = 0; nt < 4; ++nt)
#pragma unroll
                for (int r = 0; r < 4; ++r) acc[mt][nt][r] = 0.f;
        tile_mma(Tvb + (size_t)jt * 128 * 512, Bsb, tid, fa, acc);
        char* cb = Dp + (((size_t)bi * 72 + jt) * 4 + wave) * 4096;
#pragma unroll
        for (int mt = 0; mt < 4; ++mt) {
            unsigned words[4];
#pragma unroll
            for (int nt = 0; nt < 4; ++nt) {
                float rT = rTs[wn * 64 + nt * 16 + l15];
                unsigned w = 0;
#pragma unroll
                for (int k = 0; k < 4; ++k) {
                    float rIq = rIqs[wm * 64 + mt * 16 + quad * 4 + k];
                    float tt = acc[mt][nt][k] * rT;
                    rmax[mt][k] = fmaxf(rmax[mt][k], tt);
                    float qf = fmaxf(fmaf(tt, rIq, 128.0f), 0.0f);
                    w = pack_u8(qf, k, w);
                }
                words[nt] = w;
            }
            *(uint4*)(cb + mt * 1024 + lane * 16) =
                make_uint4(words[0], words[1], words[2], words[3]);
        }
    }
#pragma unroll
    for (int mt = 0; mt < 4; ++mt)
#pragma unroll
        for (int r = 0; r < 4; ++r) {
            float rm = rmax[mt][r];
            for (int off = 1; off < 16; off <<= 1)
                rm = fmaxf(rm, __shfl_xor(rm, off, 64));
            if (l15 == 0) {
                float rI = rIs[wm * 64 + mt * 16 + quad * 4 + r];
                float m = fmaxf(0.5f - 0.5f * rI * rm, 0.0f);
                atomicMin((unsigned*)(ws + OFF_MROW) + i0 + wm * 64 + mt * 16 + quad * 4 + r,
                          __float_as_uint(m));
            }
        }
}

// ---- pass 2 (stream): S'_i = sum_j exp(-a_i d_ij) over u8 D fragments ----
// grid (72, 24). c1 (incl. /255) broadcast table in LDS -> no spill.
__global__ void k_rowsum_d(float* ws) {
    __shared__ float c1s[128];
    const char* Dp = (const char*)ws + OFF_D_B;
    const int tid = threadIdx.x, lane = tid & 63, wave = tid >> 6;
    const int wm = wave >> 1, quad = (lane >> 4) & 3, l15 = lane & 15;
    const int bi = blockIdx.x;
    if (tid < 128) {
        float mm = __uint_as_float(((unsigned*)(ws + OFF_MROW))[bi * 128 + tid]);
        // -a*log2e/255
        c1s[tid] = -1.4426950408889634f / 255.0f * 2.0f / (mm + 1e-5f);
    }
    __syncthreads();
    float run[4][4];
#pragma unroll
    for (int mt = 0; mt < 4; ++mt)
#pragma unroll
        for (int r = 0; r < 4; ++r) run[mt][r] = 0.f;
    for (int t = 0; t < 3; ++t) {
        int jt = blockIdx.y * 3 + t;
        const char* cb = Dp + (((size_t)bi * 72 + jt) * 4 + wave) * 4096;
#pragma unroll
        for (int mt = 0; mt < 4; ++mt) {
            uint4 W = *(const uint4*)(cb + mt * 1024 + lane * 16);
            unsigned wd[4] = {W.x, W.y, W.z, W.w};
#pragma unroll
            for (int k = 0; k < 4; ++k) {
                float c1 = c1s[wm * 64 + mt * 16 + quad * 4 + k];
#pragma unroll
                for (int nt = 0; nt < 4; ++nt) {
                    float dq = (float)((wd[nt] >> (8 * k)) & 0xffu);
                    run[mt][k] += __builtin_amdgcn_exp2f(c1 * dq);
                }
            }
        }
    }
#pragma unroll
    for (int mt = 0; mt < 4; ++mt)
#pragma unroll
        for (int r = 0; r < 4; ++r) {
            float s = run[mt][r];
            for (int off = 1; off < 16; off <<= 1)
                s += __shfl_xor(s, off, 64);
            if (l15 == 0)
                atomicAdd(ws + OFF_WROW + bi * 128 + wm * 64 + mt * 16 + quad * 4 + r, s);
        }
}

// prep: {a_i/255, lnS'_i}  (standalone -- the r18 in-kernel fold cost +130 µs)
__global__ void k_prep(float* ws) {
    int i = blockIdx.x * 256 + threadIdx.x;
    float mm = __uint_as_float(((unsigned*)(ws + OFF_MROW))[i]);
    float a = (2.0f / 255.0f) / (mm + 1e-5f);
    float lw = logf(ws[OFF_WROW + i]);
    ((float2*)(ws + OFF_ALW))[i] = make_float2(a, lw);
}

// ---- pass 3 (stream): vcol_j = min_i [a_i d_ij + lnS'_i] over u8 D ----
// grid (72, 24). alw broadcast table in LDS -> no spill.
__global__ void k_colmin_d(float* ws) {
    __shared__ float2 alws[128];
    const char* Dp = (const char*)ws + OFF_D_B;
    const float2* alw = (const float2*)(ws + OFF_ALW);
    const int tid = threadIdx.x, lane = tid & 63, wave = tid >> 6;
    const int wm = wave >> 1, wn = wave & 1, quad = (lane >> 4) & 3, l15 = lane & 15;
    const int jt = blockIdx.x;
    float vmin[4];
#pragma unroll
    for (int nt = 0; nt < 4; ++nt) vmin[nt] = INFINITY;
    for (int t = 0; t < 3; ++t) {
        int bi = blockIdx.y * 3 + t;
        __syncthreads();  // previous iteration's readers done
        if (tid < 128) alws[tid] = alw[bi * 128 + tid];
        __syncthreads();
        const char* cb = Dp + (((size_t)bi * 72 + jt) * 4 + wave) * 4096;
#pragma unroll
        for (int mt = 0; mt < 4; ++mt) {
            uint4 W = *(const uint4*)(cb + mt * 1024 + lane * 16);
            unsigned wd[4] = {W.x, W.y, W.z, W.w};
#pragma unroll
            for (int k = 0; k < 4; ++k) {
                float2 al = alws[wm * 64 + mt * 16 + quad * 4 + k];
#pragma unroll
                for (int nt = 0; nt < 4; ++nt) {
                    float dq = (float)((wd[nt] >> (8 * k)) & 0xffu);
                    vmin[nt] = fminf(vmin[nt], al.x * dq + al.y);
                }
            }
        }
    }
    // reduce across quads (lane bits 4,5): cols shared by same l15
#pragma unroll
    for (int nt = 0; nt < 4; ++nt) {
        float v = vmin[nt];
        v = fminf(v, __shfl_xor(v, 16, 64));
        v = fminf(v, __shfl_xor(v, 32, 64));
        if (quad == 0) {
            v = fmaxf(v, 0.0f);  // keep positive-bit atomicMin valid
            atomicMin((unsigned*)(ws + OFF_VCOL) + jt * 128 + wn * 64 + nt * 16 + l15,
                      __float_as_uint(v));
        }
    }
}

// ======== FALLBACK (small ws): r8 3-GEMM path, with RI/RT scaling ========
__global__ __launch_bounds__(256, 2) void k_rowmin(float* ws) {
    __shared__ __align__(16) char Bsb[16384];
    __shared__ float rIs[128], rTs[128];
    const v8s* Ivq = (const v8s*)(ws + OFF_IV);
    const char* Tvb = (const char*)(ws + OFF_TV);
    const int tid = threadIdx.x, lane = tid & 63, wave = tid >> 6;
    const int wm = wave >> 1, wn = wave & 1, quad = (lane >> 4) & 3, l15 = lane & 15;
    const int i0 = blockIdx.x * 128;
    v8s fa[4][8];
    load_A(Ivq, i0 + wm * 64, quad, l15, fa);
    if (tid < 128) rIs[tid] = ws[OFF_RI + i0 + tid];
    float mv[4][4];
#pragma unroll
    for (int mt = 0; mt < 4; ++mt)
#pragma unroll
        for (int r = 0; r < 4; ++r) mv[mt][r] = INFINITY;
    for (int t = 0; t < 4; ++t) {
        int j0 = (blockIdx.y * 4 + t) * 128;
        __syncthreads();
        if (tid < 128) rTs[tid] = ws[OFF_RT + j0 + tid];
        v4f acc[4][4];
#pragma unroll
        for (int mt = 0; mt < 4; ++mt)
#pragma unroll
            for (int nt = 0; nt < 4; ++nt)
#pragma unroll
                for (int r = 0; r < 4; ++r) acc[mt][nt][r] = 0.f;
        tile_mma(Tvb + (size_t)j0 * 512, Bsb, tid, fa, acc);
#pragma unroll
        for (int mt = 0; mt < 4; ++mt)
#pragma unroll
            for (int nt = 0; nt < 4; ++nt) {
                float rT = rTs[wn * 64 + nt * 16 + l15];
#pragma unroll
                for (int r = 0; r < 4; ++r) {
                    float rI = rIs[wm * 64 + mt * 16 + quad * 4 + r];
                    float d = fmaxf(0.5f - 0.5f * acc[mt][nt][r] * rI * rT, 0.0f);
                    mv[mt][r] = fminf(mv[mt][r], d);
                }
            }
    }
#pragma unroll
    for (int mt = 0; mt < 4; ++mt)
#pragma unroll
        for (int r = 0; r < 4; ++r) {
            float m = mv[mt][r];
            for (int off = 1; off < 16; off <<= 1)
                m = fminf(m, __shfl_xor(m, off, 64));
            if (l15 == 0)
                atomicMin((unsigned*)(ws + OFF_MROW) + i0 + wm * 64 + mt * 16 + quad * 4 + r,
                          __float_as_uint(m));
        }
}

__global__ __launch_bounds__(256, 2) void k_rowsum(float* ws) {
    __shared__ __align__(16) char Bsb[16384];
    __shared__ float rIs[128], rTs[128];
    const v8s* Ivq = (const v8s*)(ws + OFF_IV);
    const char* Tvb = (const char*)(ws + OFF_TV);
    const int tid = threadIdx.x, lane = tid & 63, wave = tid >> 6;
    const int wm = wave >> 1, wn = wave & 1, quad = (lane >> 4) & 3, l15 = lane & 15;
    const int i0 = blockIdx.x * 128;
    v8s fa[4][8];
    load_A(Ivq, i0 + wm * 64, quad, l15, fa);
    if (tid < 128) rIs[tid] = ws[OFF_RI + i0 + tid];
    float c1[4][4], run[4][4];
#pragma unroll
    for (int mt = 0; mt < 4; ++mt)
#pragma unroll
        for (int r = 0; r < 4; ++r) {
            int i = i0 + wm * 64 + mt * 16 + quad * 4 + r;
            float mm = __uint_as_float(((unsigned*)(ws + OFF_MROW))[i]);
            c1[mt][r] = -1.4426950408889634f * 2.0f / (mm + 1e-5f);
            run[mt][r] = 0.f;
        }
    for (int t = 0; t < 4; ++t) {
        int j0 = (blockIdx.y * 4 + t) * 128;
        __syncthreads();
        if (tid < 128) rTs[tid] = ws[OFF_RT + j0 + tid];
        v4f acc[4][4];
#pragma unroll
        for (int mt = 0; mt < 4; ++mt)
#pragma unroll
            for (int nt = 0; nt < 4; ++nt)
#pragma unroll
                for (int r = 0; r < 4; ++r) acc[mt][nt][r] = 0.f;
        tile_mma(Tvb + (size_t)j0 * 512, Bsb, tid, fa, acc);
#pragma unroll
        for (int mt = 0; mt < 4; ++mt)
#pragma unroll
            for (int nt = 0; nt < 4; ++nt) {
                float rT = rTs[wn * 64 + nt * 16 + l15];
#pragma unroll
                for (int r = 0; r < 4; ++r) {
                    float rI = rIs[wm * 64 + mt * 16 + quad * 4 + r];
                    float d = fmaxf(0.5f - 0.5f * acc[mt][nt][r] * rI * rT, 0.0f);
                    run[mt][r] += __builtin_amdgcn_exp2f(c1[mt][r] * d);
                }
            }
    }
#pragma unroll
    for (int mt = 0; mt < 4; ++mt)
#pragma unroll
        for (int r = 0; r < 4; ++r) {
            float s = run[mt][r];
            for (int off = 1; off < 16; off <<= 1)
                s += __shfl_xor(s, off, 64);
            if (l15 == 0)
                atomicAdd(ws + OFF_WROW + i0 + wm * 64 + mt * 16 + quad * 4 + r, s);
        }
}

__global__ __launch_bounds__(256, 2) void k_colmin(float* ws) {
    __shared__ __align__(16) char Bsb[16384];
    __shared__ float rTsb[128], rIst[128];
    const char* Ivb = (const char*)(ws + OFF_IV);
    const v8s* Tvq = (const v8s*)(ws + OFF_TV);
    const int tid = threadIdx.x, lane = tid & 63, wave = tid >> 6;
    const int wm = wave >> 1, wn = wave & 1, quad = (lane >> 4) & 3, l15 = lane & 15;
    const int j0 = blockIdx.x * 128;
    v8s fa[4][8];
    load_A(Tvq, j0 + wm * 64, quad, l15, fa);
    if (tid < 128) rTsb[tid] = ws[OFF_RT + j0 + tid];
    float vmin[4][4];
#pragma unroll
    for (int mt = 0; mt < 4; ++mt)
#pragma unroll
        for (int r = 0; r < 4; ++r) vmin[mt][r] = INFINITY;
    for (int t = 0; t < 4; ++t) {
        int ib = (blockIdx.y * 4 + t) * 128;
        __syncthreads();
        if (tid < 128) rIst[tid] = ws[OFF_RI + ib + tid];
        v4f acc[4][4];
#pragma unroll
        for (int mt = 0; mt < 4; ++mt)
#pragma unroll
            for (int nt = 0; nt < 4; ++nt)
#pragma unroll
                for (int r = 0; r < 4; ++r) acc[mt][nt][r] = 0.f;
        tile_mma(Ivb + (size_t)ib * 512, Bsb, tid, fa, acc);  // acc = raw[j][i]
#pragma unroll
        for (int nt = 0; nt < 4; ++nt) {
            int i = ib + wn * 64 + nt * 16 + l15;
            float rI = rIst[wn * 64 + nt * 16 + l15];
            float mm = __uint_as_float(((unsigned*)(ws + OFF_MROW))[i]);
            float a = 2.0f / (mm + 1e-5f);
            float lw = __builtin_amdgcn_logf(ws[OFF_WROW + i]) * 0.6931471805599453f;
#pragma unroll
            for (int mt = 0; mt < 4; ++mt)
#pragma unroll
                for (int r = 0; r < 4; ++r) {
                    float rT = rTsb[wm * 64 + mt * 16 + quad * 4 + r];
                    float d = fmaxf(0.5f - 0.5f * acc[mt][nt][r] * rI * rT, 0.0f);
                    vmin[mt][r] = fminf(vmin[mt][r], a * d + lw);
                }
        }
    }
#pragma unroll
    for (int mt = 0; mt < 4; ++mt)
#pragma unroll
        for (int r = 0; r < 4; ++r) {
            float v = vmin[mt][r];
            for (int off = 1; off < 16; off <<= 1)
                v = fminf(v, __shfl_xor(v, off, 64));
            if (l15 == 0)
                atomicMin((unsigned*)(ws + OFF_VCOL) + j0 + wm * 64 + mt * 16 + quad * 4 + r,
                          __float_as_uint(v));
        }
}

// ------- final: parallel sum; last block writes the scalar result -------
__global__ void k_fsum(float* ws, float* __restrict__ out) {
    __shared__ float red[256];
    int j0 = blockIdx.x * 256 + threadIdx.x;
    float s = expf(-__uint_as_float(((const unsigned*)(ws + OFF_VCOL))[j0]));
    red[threadIdx.x] = s;
    __syncthreads();
    for (int off = 128; off > 0; off >>= 1) {
        if (threadIdx.x < off) red[threadIdx.x] += red[threadIdx.x + off];
        __syncthreads();
    }
    if (threadIdx.x == 0) {
        atomicAdd(ws + OFF_SUM, red[0]);
        __threadfence();
        unsigned done = atomicAdd((unsigned*)ws + OFF_CNT, 1u);
        if (done == 35u) {
            float tot = atomicAdd(ws + OFF_SUM, 0.0f);  // coherent read
            out[0] = logf((float)Sn) - logf(tot);
        }
    }
}

extern "C" void kernel_launch(void* const* d_in, const int* in_sizes, int n_in,
                              void* d_out, int out_size, void* d_ws, size_t ws_size,
                              hipStream_t stream) {
    const float* I = (const float*)d_in[0];
    const float* T = (const float*)d_in[1];
    float* ws = (float*)d_ws;
    float* out = (float*)d_out;

    k_mean<<<Cn, 256, 0, stream>>>(T, ws);
    k_norm<<<Sn / 16, 256, 0, stream>>>(I, T, ws);
    if (ws_size >= NEED_B) {
        k_gemm_d<<<dim3(72, 8), 256, 0, stream>>>(ws);
        k_rowsum_d<<<dim3(72, 24), 256, 0, stream>>>(ws);
        k_prep<<<36, 256, 0, stream>>>(ws);
        k_colmin_d<<<dim3(72, 24), 256, 0, stream>>>(ws);
    } else {
        k_rowmin<<<dim3(72, 18), 256, 0, stream>>>(ws);
        k_rowsum<<<dim3(72, 18), 256, 0, stream>>>(ws);
        k_colmin<<<dim3(72, 18), 256, 0, stream>>>(ws);
    }
    k_fsum<<<36, 256, 0, stream>>>(ws, out);
}

// Round 20
// 211.058 us; speedup vs baseline: 1.6030x; 1.0037x over previous
//
#include <hip/hip_runtime.h>
#include <math.h>

// Contextual loss, N=1, C=256, H=W=96 -> S=9216.
// loss = log(S) - log( sum_j exp( -vcol_j ) )
//   vcol_j = min_i [ a_i * d_ij + ln S'_i ],  S'_i = sum_j exp(-a_i d_ij)
//   a_i = 2/(m_i+1e-5), m_i = min_j d_ij, d = clip((1-cos)/2, 0)
// R20 = R19 (212 µs) minus the k_prep launch: colmin_d computes
// {a/255, lnS'} inline into its LDS broadcast table (r13-proven pattern,
// same as rowsum_d's c1s -- tid<128 scalar compute into LDS, NO per-thread
// arrays [r11 spill lesson], NO threadfence [r18 poison lesson]; WROW
// visibility guaranteed by the rowsum_d kernel boundary).

typedef short v8s __attribute__((ext_vector_type(8)));
typedef float v4f __attribute__((ext_vector_type(4)));

static constexpr int Sn = 9216;
static constexpr int Cn = 256;

// ws float offsets
static constexpr size_t OFF_MEAN = 0;                      // 256 floats
static constexpr size_t OFF_MROW = 256;                    // Sn uint bits (row min d)
static constexpr size_t OFF_WROW = 256 + 9216;             // Sn floats (S'_i)
static constexpr size_t OFF_VCOL = 256 + 2 * 9216;         // Sn uint bits (col min v)
static constexpr size_t OFF_SUM  = 256 + 3 * 9216;         // 1 float
static constexpr size_t OFF_CNT  = OFF_SUM + 1;            // 1 uint (fsum counter)
static constexpr size_t OFF_IV   = 65536;                  // Sn*Cn bf16 (centered)
static constexpr size_t OFF_TV   = 65536 + (size_t)Sn * Cn / 2;
static constexpr size_t OFF_RI   = 65536 + (size_t)Sn * Cn;      // Sn floats
static constexpr size_t OFF_RT   = 65536 + (size_t)Sn * Cn + Sn; // Sn floats
// u8 D in fragment layout: tile chunk (bi,jt,wave) = 4 KB.
static constexpr size_t OFF_D_B  = (size_t)16 << 20;
static constexpr size_t D_BYTES  = (size_t)72 * 72 * 4 * 4096;  // 83 MB
static constexpr size_t NEED_B   = OFF_D_B + D_BYTES;

__device__ __forceinline__ unsigned bf16rne(float x) {
    unsigned u = __float_as_uint(x);
    return (u + 0x7FFFu + ((u >> 16) & 1u)) >> 16;
}

__device__ __forceinline__ void gload_lds16(const void* g, void* l) {
    __builtin_amdgcn_global_load_lds(
        (const __attribute__((address_space(1))) unsigned*)g,
        (__attribute__((address_space(3))) unsigned*)l, 16, 0, 0);
}

__device__ __forceinline__ unsigned pack_u8(float qf, int slot, unsigned old) {
#if __has_builtin(__builtin_amdgcn_cvt_pk_u8_f32)
    return __builtin_amdgcn_cvt_pk_u8_f32(qf, slot, old);
#else
    return old | (((unsigned)fminf(qf, 255.0f)) << (8 * slot));
#endif
}

// ------- per-channel mean of T (+ absorbed init of stat buffers) -------
__global__ void k_mean(const float* __restrict__ T, float* ws) {
    __shared__ float red[256];
    int idx = blockIdx.x * 256 + threadIdx.x;
    if (idx < Sn) {
        ((unsigned*)(ws + OFF_MROW))[idx] = 0x7F800000u;  // +inf
        ws[OFF_WROW + idx] = 0.0f;
        ((unsigned*)(ws + OFF_VCOL))[idx] = 0x7F800000u;  // +inf
    }
    if (idx == 0) ws[OFF_SUM] = 0.0f;
    if (idx == 1) ((unsigned*)ws)[OFF_CNT] = 0u;

    int c = blockIdx.x;
    float s = 0.f;
    for (int i = threadIdx.x; i < Sn; i += 256) s += T[(size_t)c * Sn + i];
    red[threadIdx.x] = s;
    __syncthreads();
    for (int off = 128; off > 0; off >>= 1) {
        if (threadIdx.x < off) red[threadIdx.x] += red[threadIdx.x + off];
        __syncthreads();
    }
    if (threadIdx.x == 0) ws[OFF_MEAN + c] = red[0] * (1.0f / Sn);
}

// ------- center, emit bf16 transposed [S][C], record 1/norm (single read) ----
// 576 blocks x 256 threads: 16 positions/block, 16 channel-groups of 16.
__global__ __launch_bounds__(256) void k_norm(const float* __restrict__ I,
                                              const float* __restrict__ T,
                                              float* ws) {
    __shared__ float mc[256];
    __shared__ float redI[16][17], redT[16][17];
    const int tid = threadIdx.x, sl = tid & 15, cq = tid >> 4;
    const int s = blockIdx.x * 16 + sl;
    mc[tid] = ws[OFF_MEAN + tid];
    __syncthreads();
    unsigned short* Iv = (unsigned short*)(ws + OFF_IV);
    unsigned short* Tv = (unsigned short*)(ws + OFF_TV);
    float si = 0.f, st = 0.f;
    unsigned iw[8], tw[8];
#pragma unroll
    for (int h = 0; h < 8; ++h) {
        int c0 = cq * 16 + 2 * h, c1 = c0 + 1;
        float xi0 = I[(size_t)c0 * Sn + s] - mc[c0];
        float xi1 = I[(size_t)c1 * Sn + s] - mc[c1];
        float xt0 = T[(size_t)c0 * Sn + s] - mc[c0];
        float xt1 = T[(size_t)c1 * Sn + s] - mc[c1];
        si += xi0 * xi0 + xi1 * xi1;
        st += xt0 * xt0 + xt1 * xt1;
        iw[h] = bf16rne(xi0) | (bf16rne(xi1) << 16);
        tw[h] = bf16rne(xt0) | (bf16rne(xt1) << 16);
    }
    uint4* Ivq = (uint4*)(Iv + (size_t)s * Cn + cq * 16);
    uint4* Tvq = (uint4*)(Tv + (size_t)s * Cn + cq * 16);
    Ivq[0] = make_uint4(iw[0], iw[1], iw[2], iw[3]);
    Ivq[1] = make_uint4(iw[4], iw[5], iw[6], iw[7]);
    Tvq[0] = make_uint4(tw[0], tw[1], tw[2], tw[3]);
    Tvq[1] = make_uint4(tw[4], tw[5], tw[6], tw[7]);
    redI[sl][cq] = si;
    redT[sl][cq] = st;
    __syncthreads();
    if (tid < 16) {
        float a = 0.f, b = 0.f;
#pragma unroll
        for (int k = 0; k < 16; ++k) {
            a += redI[tid][k];
            b += redT[tid][k];
        }
        ws[OFF_RI + blockIdx.x * 16 + tid] = 1.0f / fmaxf(sqrtf(a), 1e-12f);
        ws[OFF_RT + blockIdx.x * 16 + tid] = 1.0f / fmaxf(sqrtf(b), 1e-12f);
    }
}

// ---- r3/r8-proven staging: 16 KB K-slices, 8-chunk XOR swizzle ----
__device__ __forceinline__ void stage_slice(const char* Gb, char* lds,
                                            int kcs, int tid) {
    const int lane = tid & 63, wave = tid >> 6;
#pragma unroll
    for (int w = 0; w < 4; ++w) {
        int gi = wave * 4 + w;
        int row = gi * 8 + (lane >> 3);
        int p = lane & 7;
        int c = p ^ (row & 7);
        const char* g = Gb + (size_t)row * 512 + kcs * 128 + c * 16;
        gload_lds16(g, lds + gi * 1024);
    }
}

// A fragments straight from global (L2): 32 independent 16 B loads.
__device__ __forceinline__ void load_A(const v8s* __restrict__ Aq, int row0,
                                       int quad, int l15, v8s fa[4][8]) {
#pragma unroll
    for (int mt = 0; mt < 4; ++mt) {
        size_t row = row0 + mt * 16 + l15;
#pragma unroll
        for (int kk = 0; kk < 8; ++kk)
            fa[mt][kk] = Aq[row * 32 + kk * 4 + quad];
    }
}

__device__ __forceinline__ void tile_mma(const char* Bb, char* lds, int tid,
                                         const v8s fa[4][8], v4f acc[4][4]) {
    const int lane = tid & 63, wave = tid >> 6;
    const int wn = wave & 1, quad = (lane >> 4) & 3, l15 = lane & 15;
#pragma unroll
    for (int kc = 0; kc < 4; ++kc) {
        __syncthreads();
        stage_slice(Bb, lds, kc, tid);
        __syncthreads();
#pragma unroll
        for (int ks = 0; ks < 2; ++ks) {
            int c = ks * 4 + quad;
#pragma unroll
            for (int nt = 0; nt < 4; ++nt) {
                int row = wn * 64 + nt * 16 + l15;
                int p = c ^ (row & 7);
                v8s fb = *(const v8s*)(lds + row * 128 + p * 16);
#pragma unroll
                for (int mt = 0; mt < 4; ++mt)
                    acc[mt][nt] = __builtin_amdgcn_mfma_f32_16x16x32_bf16(
                        fa[mt][kc * 2 + ks], fb, acc[mt][nt], 0, 0, 0);
            }
        }
    }
}

// ======== BIG-WS pass 1: GEMM once, store u8 D fragments + rowmin ========
__global__ __launch_bounds__(256, 2) void k_gemm_d(float* ws) {
    __shared__ __align__(16) char Bsb[16384];
    __shared__ float rIs[128], rIqs[128], rTs[128];
    const v8s* Ivq = (const v8s*)(ws + OFF_IV);
    const char* Tvb = (const char*)(ws + OFF_TV);
    char* Dp = (char*)ws + OFF_D_B;
    const int tid = threadIdx.x, lane = tid & 63, wave = tid >> 6;
    const int wm = wave >> 1, wn = wave & 1, quad = (lane >> 4) & 3, l15 = lane & 15;
    const int bi = blockIdx.x, i0 = bi * 128;
    v8s fa[4][8];
    load_A(Ivq, i0 + wm * 64, quad, l15, fa);
    if (tid < 128) {
        float rI = ws[OFF_RI + i0 + tid];
        rIs[tid] = rI;
        rIqs[tid] = -127.5f * rI;
    }
    float rmax[4][4];
#pragma unroll
    for (int mt = 0; mt < 4; ++mt)
#pragma unroll
        for (int r = 0; r < 4; ++r) rmax[mt][r] = -INFINITY;
    for (int t = 0; t < 9; ++t) {
        int jt = blockIdx.y * 9 + t;
        __syncthreads();  // epilogue readers of rTs done
        if (tid < 128) rTs[tid] = ws[OFF_RT + jt * 128 + tid];
        v4f acc[4][4];
#pragma unroll
        for (int mt = 0; mt < 4; ++mt)
#pragma unroll
            for (int nt = 0; nt < 4; ++nt)
#pragma unroll
                for (int r = 0; r < 4; ++r) acc[mt][nt][r] = 0.f;
        tile_mma(Tvb + (size_t)jt * 128 * 512, Bsb, tid, fa, acc);
        char* cb = Dp + (((size_t)bi * 72 + jt) * 4 + wave) * 4096;
#pragma unroll
        for (int mt = 0; mt < 4; ++mt) {
            unsigned words[4];
#pragma unroll
            for (int nt = 0; nt < 4; ++nt) {
                float rT = rTs[wn * 64 + nt * 16 + l15];
                unsigned w = 0;
#pragma unroll
                for (int k = 0; k < 4; ++k) {
                    float rIq = rIqs[wm * 64 + mt * 16 + quad * 4 + k];
                    float tt = acc[mt][nt][k] * rT;
                    rmax[mt][k] = fmaxf(rmax[mt][k], tt);
                    float qf = fmaxf(fmaf(tt, rIq, 128.0f), 0.0f);
                    w = pack_u8(qf, k, w);
                }
                words[nt] = w;
            }
            *(uint4*)(cb + mt * 1024 + lane * 16) =
                make_uint4(words[0], words[1], words[2], words[3]);
        }
    }
#pragma unroll
    for (int mt = 0; mt < 4; ++mt)
#pragma unroll
        for (int r = 0; r < 4; ++r) {
            float rm = rmax[mt][r];
            for (int off = 1; off < 16; off <<= 1)
                rm = fmaxf(rm, __shfl_xor(rm, off, 64));
            if (l15 == 0) {
                float rI = rIs[wm * 64 + mt * 16 + quad * 4 + r];
                float m = fmaxf(0.5f - 0.5f * rI * rm, 0.0f);
                atomicMin((unsigned*)(ws + OFF_MROW) + i0 + wm * 64 + mt * 16 + quad * 4 + r,
                          __float_as_uint(m));
            }
        }
}

// ---- pass 2 (stream): S'_i = sum_j exp(-a_i d_ij) over u8 D fragments ----
// grid (72, 24). c1 (incl. /255) broadcast table in LDS -> no spill.
__global__ void k_rowsum_d(float* ws) {
    __shared__ float c1s[128];
    const char* Dp = (const char*)ws + OFF_D_B;
    const int tid = threadIdx.x, lane = tid & 63, wave = tid >> 6;
    const int wm = wave >> 1, quad = (lane >> 4) & 3, l15 = lane & 15;
    const int bi = blockIdx.x;
    if (tid < 128) {
        float mm = __uint_as_float(((unsigned*)(ws + OFF_MROW))[bi * 128 + tid]);
        // -a*log2e/255
        c1s[tid] = -1.4426950408889634f / 255.0f * 2.0f / (mm + 1e-5f);
    }
    __syncthreads();
    float run[4][4];
#pragma unroll
    for (int mt = 0; mt < 4; ++mt)
#pragma unroll
        for (int r = 0; r < 4; ++r) run[mt][r] = 0.f;
    for (int t = 0; t < 3; ++t) {
        int jt = blockIdx.y * 3 + t;
        const char* cb = Dp + (((size_t)bi * 72 + jt) * 4 + wave) * 4096;
#pragma unroll
        for (int mt = 0; mt < 4; ++mt) {
            uint4 W = *(const uint4*)(cb + mt * 1024 + lane * 16);
            unsigned wd[4] = {W.x, W.y, W.z, W.w};
#pragma unroll
            for (int k = 0; k < 4; ++k) {
                float c1 = c1s[wm * 64 + mt * 16 + quad * 4 + k];
#pragma unroll
                for (int nt = 0; nt < 4; ++nt) {
                    float dq = (float)((wd[nt] >> (8 * k)) & 0xffu);
                    run[mt][k] += __builtin_amdgcn_exp2f(c1 * dq);
                }
            }
        }
    }
#pragma unroll
    for (int mt = 0; mt < 4; ++mt)
#pragma unroll
        for (int r = 0; r < 4; ++r) {
            float s = run[mt][r];
            for (int off = 1; off < 16; off <<= 1)
                s += __shfl_xor(s, off, 64);
            if (l15 == 0)
                atomicAdd(ws + OFF_WROW + bi * 128 + wm * 64 + mt * 16 + quad * 4 + r, s);
        }
}

// ---- pass 3 (stream): vcol_j = min_i [a_i d_ij + lnS'_i] over u8 D ----
// grid (72, 24). {a/255, lnS'} computed INLINE into the LDS broadcast
// table from MROW/WROW (k_prep launch eliminated; visibility via the
// rowsum_d kernel boundary -- no fence, no per-thread arrays).
__global__ void k_colmin_d(float* ws) {
    __shared__ float2 alws[128];
    const char* Dp = (const char*)ws + OFF_D_B;
    const int tid = threadIdx.x, lane = tid & 63, wave = tid >> 6;
    const int wm = wave >> 1, wn = wave & 1, quad = (lane >> 4) & 3, l15 = lane & 15;
    const int jt = blockIdx.x;
    float vmin[4];
#pragma unroll
    for (int nt = 0; nt < 4; ++nt) vmin[nt] = INFINITY;
    for (int t = 0; t < 3; ++t) {
        int bi = blockIdx.y * 3 + t;
        __syncthreads();  // previous iteration's readers done
        if (tid < 128) {
            int i = bi * 128 + tid;
            float mm = __uint_as_float(((unsigned*)(ws + OFF_MROW))[i]);
            float a = (2.0f / 255.0f) / (mm + 1e-5f);
            float lw = __builtin_amdgcn_logf(ws[OFF_WROW + i]) * 0.6931471805599453f;
            alws[tid] = make_float2(a, lw);
        }
        __syncthreads();
        const char* cb = Dp + (((size_t)bi * 72 + jt) * 4 + wave) * 4096;
#pragma unroll
        for (int mt = 0; mt < 4; ++mt) {
            uint4 W = *(const uint4*)(cb + mt * 1024 + lane * 16);
            unsigned wd[4] = {W.x, W.y, W.z, W.w};
#pragma unroll
            for (int k = 0; k < 4; ++k) {
                float2 al = alws[wm * 64 + mt * 16 + quad * 4 + k];
#pragma unroll
                for (int nt = 0; nt < 4; ++nt) {
                    float dq = (float)((wd[nt] >> (8 * k)) & 0xffu);
                    vmin[nt] = fminf(vmin[nt], al.x * dq + al.y);
                }
            }
        }
    }
    // reduce across quads (lane bits 4,5): cols shared by same l15
#pragma unroll
    for (int nt = 0; nt < 4; ++nt) {
        float v = vmin[nt];
        v = fminf(v, __shfl_xor(v, 16, 64));
        v = fminf(v, __shfl_xor(v, 32, 64));
        if (quad == 0) {
            v = fmaxf(v, 0.0f);  // keep positive-bit atomicMin valid
            atomicMin((unsigned*)(ws + OFF_VCOL) + jt * 128 + wn * 64 + nt * 16 + l15,
                      __float_as_uint(v));
        }
    }
}

// ======== FALLBACK (small ws): r8 3-GEMM path, with RI/RT scaling ========
__global__ __launch_bounds__(256, 2) void k_rowmin(float* ws) {
    __shared__ __align__(16) char Bsb[16384];
    __shared__ float rIs[128], rTs[128];
    const v8s* Ivq = (const v8s*)(ws + OFF_IV);
    const char* Tvb = (const char*)(ws + OFF_TV);
    const int tid = threadIdx.x, lane = tid & 63, wave = tid >> 6;
    const int wm = wave >> 1, wn = wave & 1, quad = (lane >> 4) & 3, l15 = lane & 15;
    const int i0 = blockIdx.x * 128;
    v8s fa[4][8];
    load_A(Ivq, i0 + wm * 64, quad, l15, fa);
    if (tid < 128) rIs[tid] = ws[OFF_RI + i0 + tid];
    float mv[4][4];
#pragma unroll
    for (int mt = 0; mt < 4; ++mt)
#pragma unroll
        for (int r = 0; r < 4; ++r) mv[mt][r] = INFINITY;
    for (int t = 0; t < 4; ++t) {
        int j0 = (blockIdx.y * 4 + t) * 128;
        __syncthreads();
        if (tid < 128) rTs[tid] = ws[OFF_RT + j0 + tid];
        v4f acc[4][4];
#pragma unroll
        for (int mt = 0; mt < 4; ++mt)
#pragma unroll
            for (int nt = 0; nt < 4; ++nt)
#pragma unroll
                for (int r = 0; r < 4; ++r) acc[mt][nt][r] = 0.f;
        tile_mma(Tvb + (size_t)j0 * 512, Bsb, tid, fa, acc);
#pragma unroll
        for (int mt = 0; mt < 4; ++mt)
#pragma unroll
            for (int nt = 0; nt < 4; ++nt) {
                float rT = rTs[wn * 64 + nt * 16 + l15];
#pragma unroll
                for (int r = 0; r < 4; ++r) {
                    float rI = rIs[wm * 64 + mt * 16 + quad * 4 + r];
                    float d = fmaxf(0.5f - 0.5f * acc[mt][nt][r] * rI * rT, 0.0f);
                    mv[mt][r] = fminf(mv[mt][r], d);
                }
            }
    }
#pragma unroll
    for (int mt = 0; mt < 4; ++mt)
#pragma unroll
        for (int r = 0; r < 4; ++r) {
            float m = mv[mt][r];
            for (int off = 1; off < 16; off <<= 1)
                m = fminf(m, __shfl_xor(m, off, 64));
            if (l15 == 0)
                atomicMin((unsigned*)(ws + OFF_MROW) + i0 + wm * 64 + mt * 16 + quad * 4 + r,
                          __float_as_uint(m));
        }
}

__global__ __launch_bounds__(256, 2) void k_rowsum(float* ws) {
    __shared__ __align__(16) char Bsb[16384];
    __shared__ float rIs[128], rTs[128];
    const v8s* Ivq = (const v8s*)(ws + OFF_IV);
    const char* Tvb = (const char*)(ws + OFF_TV);
    const int tid = threadIdx.x, lane = tid & 63, wave = tid >> 6;
    const int wm = wave >> 1, wn = wave & 1, quad = (lane >> 4) & 3, l15 = lane & 15;
    const int i0 = blockIdx.x * 128;
    v8s fa[4][8];
    load_A(Ivq, i0 + wm * 64, quad, l15, fa);
    if (tid < 128) rIs[tid] = ws[OFF_RI + i0 + tid];
    float c1[4][4], run[4][4];
#pragma unroll
    for (int mt = 0; mt < 4; ++mt)
#pragma unroll
        for (int r = 0; r < 4; ++r) {
            int i = i0 + wm * 64 + mt * 16 + quad * 4 + r;
            float mm = __uint_as_float(((unsigned*)(ws + OFF_MROW))[i]);
            c1[mt][r] = -1.4426950408889634f * 2.0f / (mm + 1e-5f);
            run[mt][r] = 0.f;
        }
    for (int t = 0; t < 4; ++t) {
        int j0 = (blockIdx.y * 4 + t) * 128;
        __syncthreads();
        if (tid < 128) rTs[tid] = ws[OFF_RT + j0 + tid];
        v4f acc[4][4];
#pragma unroll
        for (int mt = 0; mt < 4; ++mt)
#pragma unroll
            for (int nt = 0; nt < 4; ++nt)
#pragma unroll
                for (int r = 0; r < 4; ++r) acc[mt][nt][r] = 0.f;
        tile_mma(Tvb + (size_t)j0 * 512, Bsb, tid, fa, acc);
#pragma unroll
        for (int mt = 0; mt < 4; ++mt)
#pragma unroll
            for (int nt = 0; nt < 4; ++nt) {
                float rT = rTs[wn * 64 + nt * 16 + l15];
#pragma unroll
                for (int r = 0; r < 4; ++r) {
                    float rI = rIs[wm * 64 + mt * 16 + quad * 4 + r];
                    float d = fmaxf(0.5f - 0.5f * acc[mt][nt][r] * rI * rT, 0.0f);
                    run[mt][r] += __builtin_amdgcn_exp2f(c1[mt][r] * d);
                }
            }
    }
#pragma unroll
    for (int mt = 0; mt < 4; ++mt)
#pragma unroll
        for (int r = 0; r < 4; ++r) {
            float s = run[mt][r];
            for (int off = 1; off < 16; off <<= 1)
                s += __shfl_xor(s, off, 64);
            if (l15 == 0)
                atomicAdd(ws + OFF_WROW + i0 + wm * 64 + mt * 16 + quad * 4 + r, s);
        }
}

__global__ __launch_bounds__(256, 2) void k_colmin(float* ws) {
    __shared__ __align__(16) char Bsb[16384];
    __shared__ float rTsb[128], rIst[128];
    const char* Ivb = (const char*)(ws + OFF_IV);
    const v8s* Tvq = (const v8s*)(ws + OFF_TV);
    const int tid = threadIdx.x, lane = tid & 63, wave = tid >> 6;
    const int wm = wave >> 1, wn = wave & 1, quad = (lane >> 4) & 3, l15 = lane & 15;
    const int j0 = blockIdx.x * 128;
    v8s fa[4][8];
    load_A(Tvq, j0 + wm * 64, quad, l15, fa);
    if (tid < 128) rTsb[tid] = ws[OFF_RT + j0 + tid];
    float vmin[4][4];
#pragma unroll
    for (int mt = 0; mt < 4; ++mt)
#pragma unroll
        for (int r = 0; r < 4; ++r) vmin[mt][r] = INFINITY;
    for (int t = 0; t < 4; ++t) {
        int ib = (blockIdx.y * 4 + t) * 128;
        __syncthreads();
        if (tid < 128) rIst[tid] = ws[OFF_RI + ib + tid];
        v4f acc[4][4];
#pragma unroll
        for (int mt = 0; mt < 4; ++mt)
#pragma unroll
            for (int nt = 0; nt < 4; ++nt)
#pragma unroll
                for (int r = 0; r < 4; ++r) acc[mt][nt][r] = 0.f;
        tile_mma(Ivb + (size_t)ib * 512, Bsb, tid, fa, acc);  // acc = raw[j][i]
#pragma unroll
        for (int nt = 0; nt < 4; ++nt) {
            int i = ib + wn * 64 + nt * 16 + l15;
            float rI = rIst[wn * 64 + nt * 16 + l15];
            float mm = __uint_as_float(((unsigned*)(ws + OFF_MROW))[i]);
            float a = 2.0f / (mm + 1e-5f);
            float lw = __builtin_amdgcn_logf(ws[OFF_WROW + i]) * 0.6931471805599453f;
#pragma unroll
            for (int mt = 0; mt < 4; ++mt)
#pragma unroll
                for (int r = 0; r < 4; ++r) {
                    float rT = rTsb[wm * 64 + mt * 16 + quad * 4 + r];
                    float d = fmaxf(0.5f - 0.5f * acc[mt][nt][r] * rI * rT, 0.0f);
                    vmin[mt][r] = fminf(vmin[mt][r], a * d + lw);
                }
        }
    }
#pragma unroll
    for (int mt = 0; mt < 4; ++mt)
#pragma unroll
        for (int r = 0; r < 4; ++r) {
            float v = vmin[mt][r];
            for (int off = 1; off < 16; off <<= 1)
                v = fminf(v, __shfl_xor(v, off, 64));
            if (l15 == 0)
                atomicMin((unsigned*)(ws + OFF_VCOL) + j0 + wm * 64 + mt * 16 + quad * 4 + r,
                          __float_as_uint(v));
        }
}

// ------- final: parallel sum; last block writes the scalar result -------
__global__ void k_fsum(float* ws, float* __restrict__ out) {
    __shared__ float red[256];
    int j0 = blockIdx.x * 256 + threadIdx.x;
    float s = expf(-__uint_as_float(((const unsigned*)(ws + OFF_VCOL))[j0]));
    red[threadIdx.x] = s;
    __syncthreads();
    for (int off = 128; off > 0; off >>= 1) {
        if (threadIdx.x < off) red[threadIdx.x] += red[threadIdx.x + off];
        __syncthreads();
    }
    if (threadIdx.x == 0) {
        atomicAdd(ws + OFF_SUM, red[0]);
        __threadfence();
        unsigned done = atomicAdd((unsigned*)ws + OFF_CNT, 1u);
        if (done == 35u) {
            float tot = atomicAdd(ws + OFF_SUM, 0.0f);  // coherent read
            out[0] = logf((float)Sn) - logf(tot);
        }
    }
}

extern "C" void kernel_launch(void* const* d_in, const int* in_sizes, int n_in,
                              void* d_out, int out_size, void* d_ws, size_t ws_size,
                              hipStream_t stream) {
    const float* I = (const float*)d_in[0];
    const float* T = (const float*)d_in[1];
    float* ws = (float*)d_ws;
    float* out = (float*)d_out;

    k_mean<<<Cn, 256, 0, stream>>>(T, ws);
    k_norm<<<Sn / 16, 256, 0, stream>>>(I, T, ws);
    if (ws_size >= NEED_B) {
        k_gemm_d<<<dim3(72, 8), 256, 0, stream>>>(ws);
        k_rowsum_d<<<dim3(72, 24), 256, 0, stream>>>(ws);
        k_colmin_d<<<dim3(72, 24), 256, 0, stream>>>(ws);
    } else {
        k_rowmin<<<dim3(72, 18), 256, 0, stream>>>(ws);
        k_rowsum<<<dim3(72, 18), 256, 0, stream>>>(ws);
        k_colmin<<<dim3(72, 18), 256, 0, stream>>>(ws);
    }
    k_fsum<<<36, 256, 0, stream>>>(ws, out);
}